// Round 1
// baseline (190.026 us; speedup 1.0000x reference)
//
#include <hip/hip_runtime.h>

// MeshTokenizer: B=64 batches, NV=8192 vertices, NF=16384 faces.
// Outputs (concatenated flat, written as float32 per harness "else float*"):
//   [0]        input_ids        64 x 163841   = 10,485,824
//   [1]        attention_mask   64 x 163841   = 10,485,824
//   [2]        codes            64x16384x3x3  =  9,437,184
//   [3]        discrete_face_coords (== codes) 9,437,184
//   [4]        recon_faces      64x1x3x3      =        576
// total out_size = 39,846,592 floats

#define B_      64
#define NV_     8192
#define NF_     16384
#define ROW_    (NF_ * 10 + 1)   // 163841
#define OFF_IDS   ((size_t)0)
#define OFF_MASK  ((size_t)10485824)
#define OFF_C1    ((size_t)20971648)
#define OFF_C2    ((size_t)30408832)
#define OFF_REC   ((size_t)39846016)

// One block = 256 consecutive faces of one batch. 64 blocks/batch * 64 batches = 4096 blocks.
// Thread t (face j = j0+t) owns input_ids positions [j*10, j*10+9]:
//   pos j*10   : separator of face j-1 (128.0), or leading pad (-1.0) when j==0
//   pos j*10+1..j*10+9 : the 9 tokens of face j
// so the block covers a contiguous 2560-float span; stage in LDS, write coalesced.
__global__ __launch_bounds__(256) void mesh_tok_kernel(
        const float* __restrict__ verts,
        const int*   __restrict__ faces,
        float*       __restrict__ out) {
    const int t   = threadIdx.x;
    const int blk = blockIdx.x;
    const int b   = blk >> 6;            // batch
    const int j0  = (blk & 63) << 8;     // first face of this block
    const int j   = j0 + t;

    __shared__ float s_ids[2560];
    __shared__ float s_codes[2304];

    // ---- load face indices (3 ints) ----
    const int* fp = faces + ((size_t)b * NF_ + j) * 3;
    int vidx[3];
    vidx[0] = fp[0]; vidx[1] = fp[1]; vidx[2] = fp[2];

    // ---- gather vertices, discretize ----
    const float* vb = verts + (size_t)b * NV_ * 3;
    int code_i[9];
    #pragma unroll
    for (int vi = 0; vi < 3; ++vi) {
        const float* vp = vb + (size_t)vidx[vi] * 3;
        #pragma unroll
        for (int ci = 0; ci < 3; ++ci) {
            float x = vp[ci];
            // (x - LO)/(HI-LO)*128 - 0.5 == (x+1)*64 - 0.5 (exact same fp32 rounding)
            float q = (x + 1.0f) * 64.0f - 0.5f;
            float r = rintf(q);                       // round-half-even == jnp.round
            r = fminf(fmaxf(r, 0.0f), 127.0f);
            code_i[vi * 3 + ci] = (int)r;
        }
    }

    // ---- stage into LDS ----
    s_ids[t * 10] = (j == 0) ? -1.0f : 128.0f;
    #pragma unroll
    for (int k = 0; k < 9; ++k) {
        float cf = (float)code_i[k];
        s_ids[t * 10 + 1 + k] = cf;
        s_codes[t * 9 + k]    = cf;
    }
    __syncthreads();

    // ---- coalesced write-out ----
    float* out_ids  = out + OFF_IDS;
    float* out_mask = out + OFF_MASK;
    float* out_c1   = out + OFF_C1;
    float* out_c2   = out + OFF_C2;
    float* out_rec  = out + OFF_REC;

    const size_t base_ids = (size_t)b * ROW_ + (size_t)j0 * 10;
    #pragma unroll
    for (int k = 0; k < 10; ++k) {
        const int o = k * 256 + t;
        out_ids [base_ids + o] = s_ids[o];
        out_mask[base_ids + o] = 1.0f;
    }

    const size_t base_c = ((size_t)b * NF_ + j0) * 9;
    #pragma unroll
    for (int k = 0; k < 9; ++k) {
        const int o = k * 256 + t;
        float v = s_codes[o];
        out_c1[base_c + o] = v;
        out_c2[base_c + o] = v;
    }

    // ---- tail pad + recon_faces ----
    if (t == 0) {
        if (j0 == NF_ - 256) {   // last block of this batch writes final pad
            out_ids [(size_t)b * ROW_ + (ROW_ - 1)] = -1.0f;
            out_mask[(size_t)b * ROW_ + (ROW_ - 1)] = 1.0f;
        }
        if (j0 == 0) {           // face 0 -> recon_faces (undiscretize)
            #pragma unroll
            for (int k = 0; k < 9; ++k)
                out_rec[b * 9 + k] = ((float)code_i[k] + 0.5f) * 0.015625f - 1.0f;
        }
    }
}

extern "C" void kernel_launch(void* const* d_in, const int* in_sizes, int n_in,
                              void* d_out, int out_size, void* d_ws, size_t ws_size,
                              hipStream_t stream) {
    const float* verts = (const float*)d_in[0];
    const int*   faces = (const int*)d_in[1];
    float*       out   = (float*)d_out;

    dim3 grid(B_ * (NF_ / 256));   // 4096 blocks
    dim3 block(256);
    mesh_tok_kernel<<<grid, block, 0, stream>>>(verts, faces, out);
}